// Round 7
// baseline (484.741 us; speedup 1.0000x reference)
//
#include <hip/hip_runtime.h>
#include <hip/hip_bf16.h>
#include <stdint.h>

#define S 4096
#define E 512
#define H 8
#define D 64
#define MROW 5000        // mask row stride (MAX_GENES)

typedef __hip_bfloat16 bf16;
typedef __attribute__((ext_vector_type(8))) short bf16x8;
typedef __attribute__((ext_vector_type(4))) float f32x4;

#define CMUL (0.125f * 1.4426950408889634f)  // scale * log2(e), folded into Q

// ---------------------------------------------------------------------------
// Mask dtype sniffer (parallel, 1 wave). flag[1]=1 if byte-packed bool.
// ---------------------------------------------------------------------------
__global__ void sniff(const unsigned int* __restrict__ mask,
                      int* __restrict__ flag)
{
    int lane = threadIdx.x & 63;
    int hit = 0;
    for (int i = lane; i < 2048; i += 64) {
        unsigned int w = mask[i];
        if (w > 1u && (w & 0xFEFEFEFEu) == 0u) hit = 1;
    }
    unsigned long long b = __ballot(hit);
    if (lane == 0) { flag[1] = (b != 0ull) ? 1 : 0; flag[0] = 1; }
}

// ---------------------------------------------------------------------------
// Convert fp32 params into canonical bf16 buffers.
// ---------------------------------------------------------------------------
__global__ __launch_bounds__(256) void convert_all(
    const float* __restrict__ x,  const float* __restrict__ wq,
    const float* __restrict__ wk, const float* __restrict__ wv,
    const float* __restrict__ wo, const float* __restrict__ bq,
    const float* __restrict__ bk, const float* __restrict__ bv,
    const float* __restrict__ bo,
    bf16* __restrict__ xb, bf16* __restrict__ wcat, bf16* __restrict__ wob,
    bf16* __restrict__ bcat, bf16* __restrict__ bob)
{
    const float* srcs[9] = {x, wq, wk, wv, wo, bq, bk, bv, bo};
    bf16* dsts[9] = {xb, wcat, wcat + 262144, wcat + 524288, wob,
                     bcat, bcat + 512, bcat + 1024, bob};
    const int cnts[9] = {2097152, 262144, 262144, 262144, 262144,
                         512, 512, 512, 512};
    const int ngroups = (2097152 + 4 * 262144 + 4 * 512) / 4;
    for (int g = blockIdx.x * blockDim.x + threadIdx.x; g < ngroups;
         g += gridDim.x * blockDim.x) {
        int e = g * 4;
        int seg = 0;
        while (e >= cnts[seg]) { e -= cnts[seg]; ++seg; }
        float4 v = *(const float4*)(srcs[seg] + e);
        union { bf16 h[4]; uint2 u; } cv;
        cv.h[0] = (bf16)v.x; cv.h[1] = (bf16)v.y;
        cv.h[2] = (bf16)v.z; cv.h[3] = (bf16)v.w;
        *(uint2*)(dsts[seg] + e) = cv.u;
    }
}

// ---------------------------------------------------------------------------
// Pack mask into bit matrix bits[row][word] for the 4096x4096 region.
// ---------------------------------------------------------------------------
__global__ __launch_bounds__(256) void pack_mask(const void* __restrict__ mask,
                                                 unsigned long long* __restrict__ bits,
                                                 const int* __restrict__ flag)
{
    const bool isbyte = flag[1] != 0;
    int wid   = (blockIdx.x * blockDim.x + threadIdx.x) >> 6;
    int lane  = threadIdx.x & 63;
    int nwav  = (gridDim.x * blockDim.x) >> 6;
    int total = S * (S / 64);
    for (int w = wid; w < total; w += nwav) {
        int row  = w >> 6;
        int word = w & 63;
        int col  = word * 64 + lane;
        unsigned int v;
        if (isbyte) v = ((const unsigned char*)mask)[(size_t)row * MROW + col];
        else        v = ((const unsigned int*)mask)[(size_t)row * MROW + col];
        unsigned long long b = __ballot(v != 0u);
        if (lane == 0) bits[(size_t)row * 64 + word] = b;
    }
}

// ---------------------------------------------------------------------------
// C(64x64 tile) = A(Mx512) @ W^T + bias.
// mode 0: QKV fused (N=1536); out planar Q|K|V, Q pre-scaled by CMUL.
// mode 1: out row-major [s][512] fp32 (final projection).
// ---------------------------------------------------------------------------
__global__ __launch_bounds__(256) void gemm64(const bf16* __restrict__ A,
                                              const bf16* __restrict__ W,
                                              const bf16* __restrict__ bias,
                                              void* __restrict__ outv, int mode)
{
    __shared__ bf16 As[64][72];
    __shared__ bf16 Bs[64][72];
    const int tid  = threadIdx.x;
    const int wid  = tid >> 6, lane = tid & 63;
    const int quad = lane >> 4, l15 = lane & 15;
    const int nbase = blockIdx.x * 64;
    const int mbase = blockIdx.y * 64;
    const int m0 = wid * 16;

    f32x4 acc[4];
#pragma unroll
    for (int i = 0; i < 4; ++i) acc[i] = (f32x4){0.f, 0.f, 0.f, 0.f};

    for (int kt = 0; kt < E / 64; ++kt) {
        const int kb = kt * 64;
        __syncthreads();
#pragma unroll
        for (int i = 0; i < 2; ++i) {
            int slot = tid + i * 256;
            int row = slot >> 3, kg = slot & 7;
            *(uint4*)&As[row][kg * 8] = *(const uint4*)&A[(size_t)(mbase + row) * E + kb + kg * 8];
            *(uint4*)&Bs[row][kg * 8] = *(const uint4*)&W[(size_t)(nbase + row) * E + kb + kg * 8];
        }
        __syncthreads();
        bf16x8 a0 = *(bf16x8*)&As[m0 + l15][quad * 8];
        bf16x8 a1 = *(bf16x8*)&As[m0 + l15][32 + quad * 8];
#pragma unroll
        for (int nt = 0; nt < 4; ++nt) {
            bf16x8 b0 = *(bf16x8*)&Bs[nt * 16 + l15][quad * 8];
            bf16x8 b1 = *(bf16x8*)&Bs[nt * 16 + l15][32 + quad * 8];
            acc[nt] = __builtin_amdgcn_mfma_f32_16x16x32_bf16(a0, b0, acc[nt], 0, 0, 0);
            acc[nt] = __builtin_amdgcn_mfma_f32_16x16x32_bf16(a1, b1, acc[nt], 0, 0, 0);
        }
    }
#pragma unroll
    for (int nt = 0; nt < 4; ++nt) {
        int col = nbase + nt * 16 + l15;
        float bv = (float)bias[col];
#pragma unroll
        for (int r = 0; r < 4; ++r) {
            int row = mbase + m0 + quad * 4 + r;
            float v = acc[nt][r] + bv;
            if (mode == 0) {
                int t = col >> 9, hh = (col >> 6) & 7, d = col & 63;
                if (t == 0) v *= CMUL;
                ((bf16*)outv)[((size_t)t * H + hh) * S * D + (size_t)row * D + d] = (bf16)v;
            } else {
                ((float*)outv)[(size_t)row * E + col] = v;
            }
        }
    }
}

// ---------------------------------------------------------------------------
// Fused flash attention: 512-thread blocks (8 waves), Q-tile 128, K-tile 64,
// exp2-domain fixed softmax, K-split, register K/V prefetch, Ps aliased on Qs.
// grid: (S/128, H, nsplit). Partials: Opart[split][h][q][d], Lpart[split][h][q].
// ---------------------------------------------------------------------------
__global__ __launch_bounds__(512, 8) void attn(const bf16* __restrict__ Qp,
                                               const bf16* __restrict__ Kp,
                                               const bf16* __restrict__ Vp,
                                               const unsigned long long* __restrict__ bits,
                                               float* __restrict__ Opart,
                                               float* __restrict__ Lpart,
                                               int ktper)
{
    __shared__ __align__(16) char smem[36864];
    bf16 (*Ks)[72]  = (bf16(*)[72])smem;             //  64 x 72  (9216 B)
    bf16 (*Vts)[72] = (bf16(*)[72])(smem + 9216);    //  64 x 72  (9216 B), V^T
    bf16 (*Qs)[72]  = (bf16(*)[72])(smem + 18432);   // 128 x 72  (18432 B)
    bf16 (*Ps)[16][64] = (bf16(*)[16][64])(smem + 18432); // aliases Qs after use

    const int tid  = threadIdx.x;
    const int wid  = tid >> 6, lane = tid & 63;
    const int quad = lane >> 4, l15 = lane & 15;
    const int qt = blockIdx.x, h = blockIdx.y, split = blockIdx.z;
    const int qbase = qt * 128;
    const int m0 = wid * 16;
    const bf16* Qh = Qp + (size_t)h * S * D;
    const bf16* Kh = Kp + (size_t)h * S * D;
    const bf16* Vh = Vp + (size_t)h * S * D;

    // staging slots: K = 1 uint4/thread; V = 1 token x 8 dims/thread
    const int krow = tid >> 3, kkg = tid & 7;
    const int vt0 = tid & 63,  vd0 = (tid >> 6) * 8;

    // stage Q once (128 rows)
#pragma unroll
    for (int i = 0; i < 2; ++i) {
        int slot = tid + i * 512;
        int row = slot >> 3, kg = slot & 7;
        *(uint4*)&Qs[row][kg * 8] = *(const uint4*)&Qh[(size_t)(qbase + row) * D + kg * 8];
    }
    __syncthreads();
    bf16x8 aq0 = *(bf16x8*)&Qs[m0 + l15][quad * 8];
    bf16x8 aq1 = *(bf16x8*)&Qs[m0 + l15][32 + quad * 8];

    // ones B-fragment for l-sum MFMA (col 0 only)
    bf16x8 bl;
    {
        union { short s; bf16 b; } one; one.b = (bf16)1.0f;
        short v = (l15 == 0) ? one.s : (short)0;
#pragma unroll
        for (int j = 0; j < 8; ++j) bl[j] = v;
    }

    f32x4 o[4];
#pragma unroll
    for (int dt = 0; dt < 4; ++dt) o[dt] = (f32x4){0.f, 0.f, 0.f, 0.f};
    f32x4 accl = (f32x4){0.f, 0.f, 0.f, 0.f};

    const int kt0 = split * ktper, kt1 = kt0 + ktper;

    // prefetch tile kt0 into registers
    uint4 kq, vq;
    {
        const int kbase = kt0 * 64;
        kq = *(const uint4*)&Kh[(size_t)(kbase + krow) * D + kkg * 8];
        vq = *(const uint4*)&Vh[(size_t)(kbase + vt0) * D + vd0];
    }

    const int pkey = ((l15 >> 1) & 7);          // P read swizzle key
    for (int kt = kt0; kt < kt1; ++kt) {
        __syncthreads();   // previous tile fully consumed (also guards Qs->Ps alias)
        *(uint4*)&Ks[krow][kkg * 8] = kq;
        {
            const bf16* pv = (const bf16*)&vq;
#pragma unroll
            for (int j = 0; j < 8; ++j) Vts[vd0 + j][vt0] = pv[j];
        }
        if (kt + 1 < kt1) {
            const int kb2 = (kt + 1) * 64;
            kq = *(const uint4*)&Kh[(size_t)(kb2 + krow) * D + kkg * 8];
            vq = *(const uint4*)&Vh[(size_t)(kb2 + vt0) * D + vd0];
        }
        unsigned long long mw[4];
#pragma unroll
        for (int r = 0; r < 4; ++r) {
            int row = qbase + m0 + quad * 4 + r;
            mw[r] = bits[(size_t)row * 64 + kt];
        }
        __syncthreads();   // K/V tile visible

        // S = (Q*CMUL) K^T  (exp2 domain)
        f32x4 sc[4];
        {
            f32x4 z = (f32x4){0.f, 0.f, 0.f, 0.f};
#pragma unroll
            for (int nt = 0; nt < 4; ++nt) {
                bf16x8 b0 = *(bf16x8*)&Ks[nt * 16 + l15][quad * 8];
                bf16x8 b1 = *(bf16x8*)&Ks[nt * 16 + l15][32 + quad * 8];
                sc[nt] = __builtin_amdgcn_mfma_f32_16x16x32_bf16(aq0, b0, z, 0, 0, 0);
                sc[nt] = __builtin_amdgcn_mfma_f32_16x16x32_bf16(aq1, b1, sc[nt], 0, 0, 0);
            }
        }
        // p = exp2(s), masked -> 0; write swizzled P tile (2-way max = free)
#pragma unroll
        for (int r = 0; r < 4; ++r) {
            unsigned long long sh = mw[r] >> l15;
            int row = quad * 4 + r;
            int key = ((row >> 1) & 7) << 3;
#pragma unroll
            for (int nt = 0; nt < 4; ++nt) {
                float p = __builtin_amdgcn_exp2f(sc[nt][r]);
                bool ok = (sh >> (nt * 16)) & 1ull;
                p = ok ? p : 0.f;
                Ps[wid][row][(nt * 16 + l15) ^ key] = (bf16)p;
            }
        }
        // O += P V ; l += P 1
        bf16x8 ap0 = *(bf16x8*)&Ps[wid][l15][(quad ^ pkey) * 8];
        bf16x8 ap1 = *(bf16x8*)&Ps[wid][l15][((quad + 4) ^ pkey) * 8];
        accl = __builtin_amdgcn_mfma_f32_16x16x32_bf16(ap0, bl, accl, 0, 0, 0);
        accl = __builtin_amdgcn_mfma_f32_16x16x32_bf16(ap1, bl, accl, 0, 0, 0);
#pragma unroll
        for (int dt = 0; dt < 4; ++dt) {
            bf16x8 bv0 = *(bf16x8*)&Vts[dt * 16 + l15][quad * 8];
            bf16x8 bv1 = *(bf16x8*)&Vts[dt * 16 + l15][32 + quad * 8];
            o[dt] = __builtin_amdgcn_mfma_f32_16x16x32_bf16(ap0, bv0, o[dt], 0, 0, 0);
            o[dt] = __builtin_amdgcn_mfma_f32_16x16x32_bf16(ap1, bv1, o[dt], 0, 0, 0);
        }
    }
    // epilogue: store fp32 partials; l lives in lanes l15==0 (col 0 of accl)
    float* Op = Opart + (size_t)(split * H + h) * S * D;
    float* Lp = Lpart + (size_t)(split * H + h) * S;
#pragma unroll
    for (int r = 0; r < 4; ++r) {
        int row = qbase + m0 + quad * 4 + r;
        if (l15 == 0) Lp[row] = accl[r];
#pragma unroll
        for (int dt = 0; dt < 4; ++dt)
            Op[(size_t)row * D + dt * 16 + l15] = o[dt][r];
    }
}

// ---------------------------------------------------------------------------
// Combine K-split partials: Ow[s][h*64+d] = sum_s Opart / sum_s Lpart (bf16).
// ---------------------------------------------------------------------------
__global__ __launch_bounds__(256) void combine(const float* __restrict__ Opart,
                                               const float* __restrict__ Lpart,
                                               bf16* __restrict__ Ow, int nsplit)
{
    int g = blockIdx.x * 256 + threadIdx.x;
    int e = g * 4;
    int row = e >> 9;
    int c = e & 511;
    int h = c >> 6, d = c & 63;
    size_t base = ((size_t)h * S + row) * D + d;
    const size_t oh = (size_t)H * S * D;
    float ax = 0.f, ay = 0.f, az = 0.f, aw = 0.f, l = 0.f;
    for (int s = 0; s < nsplit; ++s) {
        float4 a = *(const float4*)(Opart + (size_t)s * oh + base);
        ax += a.x; ay += a.y; az += a.z; aw += a.w;
        l += Lpart[(size_t)s * H * S + (size_t)h * S + row];
    }
    float inv = (l > 0.f) ? 1.f / l : 0.f;
    union { bf16 x[4]; uint2 u; } ov;
    ov.x[0] = (bf16)(ax * inv);
    ov.x[1] = (bf16)(ay * inv);
    ov.x[2] = (bf16)(az * inv);
    ov.x[3] = (bf16)(aw * inv);
    *(uint2*)(Ow + (size_t)row * E + c) = ov.u;
}

// ---------------------------------------------------------------------------
extern "C" void kernel_launch(void* const* d_in, const int* in_sizes, int n_in,
                              void* d_out, int out_size, void* d_ws, size_t ws_size,
                              hipStream_t stream)
{
    char* ws = (char*)d_ws;
    const size_t MB = (size_t)1 << 20;
    bf16* Qw   = (bf16*)(ws + 0 * MB);        // 12 MB: Q|K|V planar cat
    bf16* Kw   = (bf16*)(ws + 4 * MB);
    bf16* Vw   = (bf16*)(ws + 8 * MB);
    bf16* Ow   = (bf16*)(ws + 12 * MB);       // 4 MB [s][512] bf16
    unsigned long long* bits = (unsigned long long*)(ws + 16 * MB); // 2 MB
    bf16* xb   = (bf16*)(ws + 18 * MB);       // 4 MB
    bf16* Wcat = (bf16*)(ws + 22 * MB);       // 1.5 MB
    bf16* Wob  = (bf16*)(ws + 24 * MB);       // 0.5 MB
    bf16* bcat = (bf16*)(ws + 25 * MB);
    bf16* bob  = (bf16*)(ws + 25 * MB + 8192);
    int*  flag = (int*)(ws + 25 * MB + 16384);
    float* Opart = (float*)(ws + 26 * MB);    // nsplit x 8 MB

    // ws-size-adaptive K-split (deterministic across calls)
    int nsplit = (ws_size >= 60 * MB) ? 4 : 2;
    int ktper  = (S / 64) / nsplit;
    float* Lpart = (float*)(ws + 26 * MB + (size_t)nsplit * 8 * MB);

    hipLaunchKernelGGL(sniff, dim3(1), dim3(64), 0, stream,
                       (const unsigned int*)d_in[9], flag);
    hipLaunchKernelGGL(convert_all, dim3(1024), dim3(256), 0, stream,
                       (const float*)d_in[0], (const float*)d_in[1],
                       (const float*)d_in[3], (const float*)d_in[5],
                       (const float*)d_in[7], (const float*)d_in[2],
                       (const float*)d_in[4], (const float*)d_in[6],
                       (const float*)d_in[8],
                       xb, Wcat, Wob, bcat, bob);
    hipLaunchKernelGGL(pack_mask, dim3(1024), dim3(256), 0, stream, d_in[9], bits, flag);
    hipLaunchKernelGGL(gemm64, dim3(24, 64), dim3(256), 0, stream, xb, Wcat, bcat, (void*)Qw, 0);
    hipLaunchKernelGGL(attn, dim3(S / 128, H, nsplit), dim3(512), 0, stream,
                       Qw, Kw, Vw, bits, Opart, Lpart, ktper);
    hipLaunchKernelGGL(combine, dim3(2048), dim3(256), 0, stream, Opart, Lpart, Ow, nsplit);
    hipLaunchKernelGGL(gemm64, dim3(8, 64), dim3(256), 0, stream, Ow, Wob, bob, d_out, 1);
}

// Round 8
// 313.576 us; speedup vs baseline: 1.5458x; 1.5458x over previous
//
#include <hip/hip_runtime.h>
#include <hip/hip_bf16.h>
#include <stdint.h>

#define S 4096
#define E 512
#define H 8
#define D 64
#define MROW 5000        // mask row stride (MAX_GENES)

typedef __hip_bfloat16 bf16;
typedef __attribute__((ext_vector_type(8))) short bf16x8;
typedef __attribute__((ext_vector_type(4))) float f32x4;

#define CMUL (0.125f * 1.4426950408889634f)  // scale * log2(e), folded into Q

// ---------------------------------------------------------------------------
// Mask dtype sniffer (parallel, 1 wave). flag[1]=1 if byte-packed bool.
// ---------------------------------------------------------------------------
__global__ void sniff(const unsigned int* __restrict__ mask,
                      int* __restrict__ flag)
{
    int lane = threadIdx.x & 63;
    int hit = 0;
    for (int i = lane; i < 2048; i += 64) {
        unsigned int w = mask[i];
        if (w > 1u && (w & 0xFEFEFEFEu) == 0u) hit = 1;
    }
    unsigned long long b = __ballot(hit);
    if (lane == 0) { flag[1] = (b != 0ull) ? 1 : 0; flag[0] = 1; }
}

// ---------------------------------------------------------------------------
// Convert fp32 params into canonical bf16 buffers.
// ---------------------------------------------------------------------------
__global__ __launch_bounds__(256) void convert_all(
    const float* __restrict__ x,  const float* __restrict__ wq,
    const float* __restrict__ wk, const float* __restrict__ wv,
    const float* __restrict__ wo, const float* __restrict__ bq,
    const float* __restrict__ bk, const float* __restrict__ bv,
    const float* __restrict__ bo,
    bf16* __restrict__ xb, bf16* __restrict__ wcat, bf16* __restrict__ wob,
    bf16* __restrict__ bcat, bf16* __restrict__ bob)
{
    const float* srcs[9] = {x, wq, wk, wv, wo, bq, bk, bv, bo};
    bf16* dsts[9] = {xb, wcat, wcat + 262144, wcat + 524288, wob,
                     bcat, bcat + 512, bcat + 1024, bob};
    const int cnts[9] = {2097152, 262144, 262144, 262144, 262144,
                         512, 512, 512, 512};
    const int ngroups = (2097152 + 4 * 262144 + 4 * 512) / 4;
    for (int g = blockIdx.x * blockDim.x + threadIdx.x; g < ngroups;
         g += gridDim.x * blockDim.x) {
        int e = g * 4;
        int seg = 0;
        while (e >= cnts[seg]) { e -= cnts[seg]; ++seg; }
        float4 v = *(const float4*)(srcs[seg] + e);
        union { bf16 h[4]; uint2 u; } cv;
        cv.h[0] = (bf16)v.x; cv.h[1] = (bf16)v.y;
        cv.h[2] = (bf16)v.z; cv.h[3] = (bf16)v.w;
        *(uint2*)(dsts[seg] + e) = cv.u;
    }
}

// ---------------------------------------------------------------------------
// Pack mask into bit matrix bits[row][word] for the 4096x4096 region.
// ---------------------------------------------------------------------------
__global__ __launch_bounds__(256) void pack_mask(const void* __restrict__ mask,
                                                 unsigned long long* __restrict__ bits,
                                                 const int* __restrict__ flag)
{
    const bool isbyte = flag[1] != 0;
    int wid   = (blockIdx.x * blockDim.x + threadIdx.x) >> 6;
    int lane  = threadIdx.x & 63;
    int nwav  = (gridDim.x * blockDim.x) >> 6;
    int total = S * (S / 64);
    for (int w = wid; w < total; w += nwav) {
        int row  = w >> 6;
        int word = w & 63;
        int col  = word * 64 + lane;
        unsigned int v;
        if (isbyte) v = ((const unsigned char*)mask)[(size_t)row * MROW + col];
        else        v = ((const unsigned int*)mask)[(size_t)row * MROW + col];
        unsigned long long b = __ballot(v != 0u);
        if (lane == 0) bits[(size_t)row * 64 + word] = b;
    }
}

// ---------------------------------------------------------------------------
// C(64x64 tile) = A(Mx512) @ W^T + bias.
// mode 0: QKV fused (N=1536); out planar Q|K|V, Q pre-scaled by CMUL.
// mode 1: out row-major [s][512] fp32 (final projection).
// ---------------------------------------------------------------------------
__global__ __launch_bounds__(256) void gemm64(const bf16* __restrict__ A,
                                              const bf16* __restrict__ W,
                                              const bf16* __restrict__ bias,
                                              void* __restrict__ outv, int mode)
{
    __shared__ bf16 As[64][72];
    __shared__ bf16 Bs[64][72];
    const int tid  = threadIdx.x;
    const int wid  = tid >> 6, lane = tid & 63;
    const int quad = lane >> 4, l15 = lane & 15;
    const int nbase = blockIdx.x * 64;
    const int mbase = blockIdx.y * 64;
    const int m0 = wid * 16;

    f32x4 acc[4];
#pragma unroll
    for (int i = 0; i < 4; ++i) acc[i] = (f32x4){0.f, 0.f, 0.f, 0.f};

    for (int kt = 0; kt < E / 64; ++kt) {
        const int kb = kt * 64;
        __syncthreads();
#pragma unroll
        for (int i = 0; i < 2; ++i) {
            int slot = tid + i * 256;
            int row = slot >> 3, kg = slot & 7;
            *(uint4*)&As[row][kg * 8] = *(const uint4*)&A[(size_t)(mbase + row) * E + kb + kg * 8];
            *(uint4*)&Bs[row][kg * 8] = *(const uint4*)&W[(size_t)(nbase + row) * E + kb + kg * 8];
        }
        __syncthreads();
        bf16x8 a0 = *(bf16x8*)&As[m0 + l15][quad * 8];
        bf16x8 a1 = *(bf16x8*)&As[m0 + l15][32 + quad * 8];
#pragma unroll
        for (int nt = 0; nt < 4; ++nt) {
            bf16x8 b0 = *(bf16x8*)&Bs[nt * 16 + l15][quad * 8];
            bf16x8 b1 = *(bf16x8*)&Bs[nt * 16 + l15][32 + quad * 8];
            acc[nt] = __builtin_amdgcn_mfma_f32_16x16x32_bf16(a0, b0, acc[nt], 0, 0, 0);
            acc[nt] = __builtin_amdgcn_mfma_f32_16x16x32_bf16(a1, b1, acc[nt], 0, 0, 0);
        }
    }
#pragma unroll
    for (int nt = 0; nt < 4; ++nt) {
        int col = nbase + nt * 16 + l15;
        float bv = (float)bias[col];
#pragma unroll
        for (int r = 0; r < 4; ++r) {
            int row = mbase + m0 + quad * 4 + r;
            float v = acc[nt][r] + bv;
            if (mode == 0) {
                int t = col >> 9, hh = (col >> 6) & 7, d = col & 63;
                if (t == 0) v *= CMUL;
                ((bf16*)outv)[((size_t)t * H + hh) * S * D + (size_t)row * D + d] = (bf16)v;
            } else {
                ((float*)outv)[(size_t)row * E + col] = v;
            }
        }
    }
}

// ---------------------------------------------------------------------------
// Fused flash attention. 256-thread blocks (4 waves), Q-tile 64, K-tile 64.
// LDS 25600 B: Ks/Vts unpadded 64x64 with XOR swizzle col^=(row&7)*8;
// Ps aliased onto Qs. exp2-domain fixed softmax, K-split, reg K/V prefetch.
// grid: (S/64, H, nsplit).
// ---------------------------------------------------------------------------
__global__ __launch_bounds__(256) void attn(const bf16* __restrict__ Qp,
                                            const bf16* __restrict__ Kp,
                                            const bf16* __restrict__ Vp,
                                            const unsigned long long* __restrict__ bits,
                                            float* __restrict__ Opart,
                                            float* __restrict__ Lpart,
                                            int ktper)
{
    __shared__ __align__(16) char smem[25600];
    bf16 (*Qs)[72]     = (bf16(*)[72])smem;                 // 64x72 (9216 B)
    bf16 (*Ps)[16][64] = (bf16(*)[16][64])smem;             // aliases Qs after use
    bf16 (*Ks)[64]     = (bf16(*)[64])(smem + 9216);        // 64x64 swizzled (8192 B)
    bf16 (*Vts)[64]    = (bf16(*)[64])(smem + 17408);       // 64x64 swizzled V^T (8192 B)

    const int tid  = threadIdx.x;
    const int wid  = tid >> 6, lane = tid & 63;
    const int quad = lane >> 4, l15 = lane & 15;
    const int qt = blockIdx.x, h = blockIdx.y, split = blockIdx.z;
    const int qbase = qt * 64;
    const int m0 = wid * 16;
    const bf16* Qh = Qp + (size_t)h * S * D;
    const bf16* Kh = Kp + (size_t)h * S * D;
    const bf16* Vh = Vp + (size_t)h * S * D;

    // staging slots: K = 2 uint4/thread (rows krow0/krow1, swizzled col)
    const int krow0 = tid >> 3, kkg = tid & 7;
    const int krow1 = (tid + 256) >> 3;
    const int ksw0 = (kkg ^ (krow0 & 7)) * 8;
    const int ksw1 = (kkg ^ (krow1 & 7)) * 8;
    // V: 2 tokens x 8 dims/thread; rows vd0..vd0+7, swizzled col = vt0^(j*8)
    const int vt0 = (tid & 31) * 2, vd0 = (tid >> 5) * 8;

    // stage Q once (64 rows, 72-padded region)
#pragma unroll
    for (int i = 0; i < 2; ++i) {
        int slot = tid + i * 256;
        int row = slot >> 3, kg = slot & 7;
        *(uint4*)&Qs[row][kg * 8] = *(const uint4*)&Qh[(size_t)(qbase + row) * D + kg * 8];
    }
    __syncthreads();
    bf16x8 aq0 = *(bf16x8*)&Qs[m0 + l15][quad * 8];
    bf16x8 aq1 = *(bf16x8*)&Qs[m0 + l15][32 + quad * 8];

    // ones B-fragment for l-sum MFMA (col 0 only)
    bf16x8 bl;
    {
        union { short s; bf16 b; } one; one.b = (bf16)1.0f;
        short v = (l15 == 0) ? one.s : (short)0;
#pragma unroll
        for (int j = 0; j < 8; ++j) bl[j] = v;
    }

    f32x4 o[4];
#pragma unroll
    for (int dt = 0; dt < 4; ++dt) o[dt] = (f32x4){0.f, 0.f, 0.f, 0.f};
    f32x4 accl = (f32x4){0.f, 0.f, 0.f, 0.f};

    const int kt0 = split * ktper, kt1 = kt0 + ktper;

    // prefetch tile kt0 into registers
    uint4 kq0, kq1, vq0, vq1;
    {
        const int kbase = kt0 * 64;
        kq0 = *(const uint4*)&Kh[(size_t)(kbase + krow0) * D + kkg * 8];
        kq1 = *(const uint4*)&Kh[(size_t)(kbase + krow1) * D + kkg * 8];
        vq0 = *(const uint4*)&Vh[(size_t)(kbase + vt0) * D + vd0];
        vq1 = *(const uint4*)&Vh[(size_t)(kbase + vt0 + 1) * D + vd0];
    }

    const int ksw_rd = (l15 & 7);               // K/V read swizzle key
    const int pkey   = ((l15 >> 1) & 7);        // Ps read swizzle key
    for (int kt = kt0; kt < kt1; ++kt) {
        __syncthreads();   // previous tile consumed (guards Qs->Ps alias too)
        *(uint4*)&Ks[krow0][ksw0] = kq0;
        *(uint4*)&Ks[krow1][ksw1] = kq1;
        {
            const unsigned short* p0 = (const unsigned short*)&vq0;
            const unsigned short* p1 = (const unsigned short*)&vq1;
#pragma unroll
            for (int j = 0; j < 8; ++j) {
                unsigned int pk = (unsigned int)p0[j] | ((unsigned int)p1[j] << 16);
                *(unsigned int*)&Vts[vd0 + j][vt0 ^ (j * 8)] = pk;
            }
        }
        if (kt + 1 < kt1) {
            const int kb2 = (kt + 1) * 64;
            kq0 = *(const uint4*)&Kh[(size_t)(kb2 + krow0) * D + kkg * 8];
            kq1 = *(const uint4*)&Kh[(size_t)(kb2 + krow1) * D + kkg * 8];
            vq0 = *(const uint4*)&Vh[(size_t)(kb2 + vt0) * D + vd0];
            vq1 = *(const uint4*)&Vh[(size_t)(kb2 + vt0 + 1) * D + vd0];
        }
        unsigned long long mw[4];
#pragma unroll
        for (int r = 0; r < 4; ++r) {
            int row = qbase + m0 + quad * 4 + r;
            mw[r] = bits[(size_t)row * 64 + kt];
        }
        __syncthreads();   // K/V tile visible

        // S = (Q*CMUL) K^T  (exp2 domain); K rows swizzle-read
        f32x4 sc[4];
        {
            f32x4 z = (f32x4){0.f, 0.f, 0.f, 0.f};
#pragma unroll
            for (int nt = 0; nt < 4; ++nt) {
                bf16x8 b0 = *(bf16x8*)&Ks[nt * 16 + l15][(quad ^ ksw_rd) * 8];
                bf16x8 b1 = *(bf16x8*)&Ks[nt * 16 + l15][((quad + 4) ^ ksw_rd) * 8];
                sc[nt] = __builtin_amdgcn_mfma_f32_16x16x32_bf16(aq0, b0, z, 0, 0, 0);
                sc[nt] = __builtin_amdgcn_mfma_f32_16x16x32_bf16(aq1, b1, sc[nt], 0, 0, 0);
            }
        }
        // p = exp2(s), masked -> 0; write swizzled P tile
#pragma unroll
        for (int r = 0; r < 4; ++r) {
            unsigned long long sh = mw[r] >> l15;
            int row = quad * 4 + r;
            int key = ((row >> 1) & 7) << 3;
#pragma unroll
            for (int nt = 0; nt < 4; ++nt) {
                float p = __builtin_amdgcn_exp2f(sc[nt][r]);
                bool ok = (sh >> (nt * 16)) & 1ull;
                p = ok ? p : 0.f;
                Ps[wid][row][(nt * 16 + l15) ^ key] = (bf16)p;
            }
        }
        // O += P V ; l += P 1
        bf16x8 ap0 = *(bf16x8*)&Ps[wid][l15][(quad ^ pkey) * 8];
        bf16x8 ap1 = *(bf16x8*)&Ps[wid][l15][((quad + 4) ^ pkey) * 8];
        accl = __builtin_amdgcn_mfma_f32_16x16x32_bf16(ap0, bl, accl, 0, 0, 0);
        accl = __builtin_amdgcn_mfma_f32_16x16x32_bf16(ap1, bl, accl, 0, 0, 0);
#pragma unroll
        for (int dt = 0; dt < 4; ++dt) {
            bf16x8 bv0 = *(bf16x8*)&Vts[dt * 16 + l15][(quad ^ ksw_rd) * 8];
            bf16x8 bv1 = *(bf16x8*)&Vts[dt * 16 + l15][((quad + 4) ^ ksw_rd) * 8];
            o[dt] = __builtin_amdgcn_mfma_f32_16x16x32_bf16(ap0, bv0, o[dt], 0, 0, 0);
            o[dt] = __builtin_amdgcn_mfma_f32_16x16x32_bf16(ap1, bv1, o[dt], 0, 0, 0);
        }
    }
    // epilogue: store fp32 partials; l lives in lanes l15==0 (col 0 of accl)
    float* Op = Opart + (size_t)(split * H + h) * S * D;
    float* Lp = Lpart + (size_t)(split * H + h) * S;
#pragma unroll
    for (int r = 0; r < 4; ++r) {
        int row = qbase + m0 + quad * 4 + r;
        if (l15 == 0) Lp[row] = accl[r];
#pragma unroll
        for (int dt = 0; dt < 4; ++dt)
            Op[(size_t)row * D + dt * 16 + l15] = o[dt][r];
    }
}

// ---------------------------------------------------------------------------
// Combine K-split partials: Ow[s][h*64+d] = sum_s Opart / sum_s Lpart (bf16).
// ---------------------------------------------------------------------------
__global__ __launch_bounds__(256) void combine(const float* __restrict__ Opart,
                                               const float* __restrict__ Lpart,
                                               bf16* __restrict__ Ow, int nsplit)
{
    int g = blockIdx.x * 256 + threadIdx.x;
    int e = g * 4;
    int row = e >> 9;
    int c = e & 511;
    int h = c >> 6, d = c & 63;
    size_t base = ((size_t)h * S + row) * D + d;
    const size_t oh = (size_t)H * S * D;
    float ax = 0.f, ay = 0.f, az = 0.f, aw = 0.f, l = 0.f;
    for (int s = 0; s < nsplit; ++s) {
        float4 a = *(const float4*)(Opart + (size_t)s * oh + base);
        ax += a.x; ay += a.y; az += a.z; aw += a.w;
        l += Lpart[(size_t)s * H * S + (size_t)h * S + row];
    }
    float inv = (l > 0.f) ? 1.f / l : 0.f;
    union { bf16 x[4]; uint2 u; } ov;
    ov.x[0] = (bf16)(ax * inv);
    ov.x[1] = (bf16)(ay * inv);
    ov.x[2] = (bf16)(az * inv);
    ov.x[3] = (bf16)(aw * inv);
    *(uint2*)(Ow + (size_t)row * E + c) = ov.u;
}

// ---------------------------------------------------------------------------
extern "C" void kernel_launch(void* const* d_in, const int* in_sizes, int n_in,
                              void* d_out, int out_size, void* d_ws, size_t ws_size,
                              hipStream_t stream)
{
    char* ws = (char*)d_ws;
    const size_t MB = (size_t)1 << 20;
    bf16* Qw   = (bf16*)(ws + 0 * MB);        // 12 MB: Q|K|V planar cat
    bf16* Kw   = (bf16*)(ws + 4 * MB);
    bf16* Vw   = (bf16*)(ws + 8 * MB);
    bf16* Ow   = (bf16*)(ws + 12 * MB);       // 4 MB [s][512] bf16
    unsigned long long* bits = (unsigned long long*)(ws + 16 * MB); // 2 MB
    bf16* xb   = (bf16*)(ws + 18 * MB);       // 4 MB
    bf16* Wcat = (bf16*)(ws + 22 * MB);       // 1.5 MB
    bf16* Wob  = (bf16*)(ws + 24 * MB);       // 0.5 MB
    bf16* bcat = (bf16*)(ws + 25 * MB);
    bf16* bob  = (bf16*)(ws + 25 * MB + 8192);
    int*  flag = (int*)(ws + 25 * MB + 16384);
    float* Opart = (float*)(ws + 26 * MB);    // nsplit x 8 MB

    // ws-size-adaptive K-split (deterministic across calls)
    int nsplit = (ws_size >= 59 * MB) ? 4 : 2;
    int ktper  = (S / 64) / nsplit;
    float* Lpart = (float*)(ws + 26 * MB + (size_t)nsplit * 8 * MB);

    hipLaunchKernelGGL(sniff, dim3(1), dim3(64), 0, stream,
                       (const unsigned int*)d_in[9], flag);
    hipLaunchKernelGGL(convert_all, dim3(1024), dim3(256), 0, stream,
                       (const float*)d_in[0], (const float*)d_in[1],
                       (const float*)d_in[3], (const float*)d_in[5],
                       (const float*)d_in[7], (const float*)d_in[2],
                       (const float*)d_in[4], (const float*)d_in[6],
                       (const float*)d_in[8],
                       xb, Wcat, Wob, bcat, bob);
    hipLaunchKernelGGL(pack_mask, dim3(1024), dim3(256), 0, stream, d_in[9], bits, flag);
    hipLaunchKernelGGL(gemm64, dim3(24, 64), dim3(256), 0, stream, xb, Wcat, bcat, (void*)Qw, 0);
    hipLaunchKernelGGL(attn, dim3(S / 64, H, nsplit), dim3(256), 0, stream,
                       Qw, Kw, Vw, bits, Opart, Lpart, ktper);
    hipLaunchKernelGGL(combine, dim3(2048), dim3(256), 0, stream, Opart, Lpart, Ow, nsplit);
    hipLaunchKernelGGL(gemm64, dim3(8, 64), dim3(256), 0, stream, Ow, Wob, bob, d_out, 1);
}